// Round 13
// baseline (379.238 us; speedup 1.0000x reference)
//
#include <hip/hip_runtime.h>
#include <math.h>

#define SCAN_B 1024

typedef __attribute__((ext_vector_type(8))) short short8v;
typedef __attribute__((ext_vector_type(8))) unsigned short ushort8v;
typedef __attribute__((ext_vector_type(4))) float f32x4;

static inline int ceil_div_i(long long a, int b) { return (int)((a + b - 1) / b); }

__device__ __forceinline__ unsigned short f2bf(float x) {
    unsigned int u = __float_as_uint(x);
    u += 0x7fffu + ((u >> 16) & 1u);   // round-to-nearest-even
    return (unsigned short)(u >> 16);
}
__device__ __forceinline__ float bf2f(unsigned short h) {
    return __uint_as_float(((unsigned int)h) << 16);
}
__device__ __forceinline__ ushort8v zero8() {
    ushort8v z;
#pragma unroll
    for (int e = 0; e < 8; e++) z[e] = 0;
    return z;
}

// ---------------- CSR construction ----------------

__global__ __launch_bounds__(256) void k_count(const int* __restrict__ dst, int E,
                                               int* __restrict__ cnt) {
    int i = blockIdx.x * blockDim.x + threadIdx.x;
    if (i < E) atomicAdd(&cnt[dst[i]], 1);
}

__global__ __launch_bounds__(256) void k_dinv(const int* __restrict__ cnt,
                                              float* __restrict__ dinv, int N) {
    int i = blockIdx.x * blockDim.x + threadIdx.x;
    if (i < N) dinv[i] = (float)(1.0 / sqrt((double)(cnt[i] + 1)));
}

__global__ __launch_bounds__(256) void k_scan1(const int* __restrict__ cnt,
                                               int* __restrict__ rowptr,
                                               int* __restrict__ bsum, int N) {
    __shared__ int s[256];
    int tid = threadIdx.x;
    int base = blockIdx.x * SCAN_B + tid * 4;
    int a0 = (base + 0 < N) ? cnt[base + 0] : 0;
    int a1 = (base + 1 < N) ? cnt[base + 1] : 0;
    int a2 = (base + 2 < N) ? cnt[base + 2] : 0;
    int a3 = (base + 3 < N) ? cnt[base + 3] : 0;
    int tsum = a0 + a1 + a2 + a3;
    s[tid] = tsum;
    __syncthreads();
    for (int off = 1; off < 256; off <<= 1) {
        int val = 0;
        if (tid >= off) val = s[tid - off];
        __syncthreads();
        if (tid >= off) s[tid] += val;
        __syncthreads();
    }
    int texcl = s[tid] - tsum;
    if (tid == 255) bsum[blockIdx.x] = s[255];
    if (base + 0 < N) rowptr[base + 0] = texcl;
    if (base + 1 < N) rowptr[base + 1] = texcl + a0;
    if (base + 2 < N) rowptr[base + 2] = texcl + a0 + a1;
    if (base + 3 < N) rowptr[base + 3] = texcl + a0 + a1 + a2;
}

__global__ __launch_bounds__(256) void k_scan2(int* __restrict__ bsum, int NB) {
    __shared__ int s[256];
    int tid = threadIdx.x;
    int v = (tid < NB) ? bsum[tid] : 0;
    s[tid] = v;
    __syncthreads();
    for (int off = 1; off < 256; off <<= 1) {
        int val = 0;
        if (tid >= off) val = s[tid - off];
        __syncthreads();
        if (tid >= off) s[tid] += val;
        __syncthreads();
    }
    if (tid < NB) bsum[tid] = s[tid] - v;
}

__global__ __launch_bounds__(256) void k_scan3(int* __restrict__ rowptr,
                                               const int* __restrict__ bsum, int N, int E) {
    int i = blockIdx.x * blockDim.x + threadIdx.x;
    if (i < N) rowptr[i] += bsum[i >> 10];
    if (i == 0) rowptr[N] = E;
}

// fill writes ONLY col (edge weights eliminated algebraically via dinv pre-scaling)
__global__ __launch_bounds__(256) void k_fill(const int* __restrict__ src,
                                              const int* __restrict__ dst, int E,
                                              const int* __restrict__ rowptr,
                                              int* __restrict__ fill,
                                              int* __restrict__ col) {
    int e = blockIdx.x * blockDim.x + threadIdx.x;
    if (e >= E) return;
    int s = src[e], d = dst[e];
    int pos = atomicAdd(&fill[d], 1);
    col[rowptr[d] + pos] = s;
}

// ---------------- scale+pad x -> bf16: Y[v][c] = bf16(dinv[v]*x[v][c]), stride XS ------

__global__ __launch_bounds__(256) void k_xscale(const float* __restrict__ x,
                                                const float* __restrict__ dinv,
                                                unsigned short* __restrict__ xb,
                                                int N, int F, int XS) {
    int i = blockIdx.x * blockDim.x + threadIdx.x;
    int v = i / XS, c = i - v * XS;
    if (v >= N) return;
    float val = (c < F) ? dinv[v] * x[(size_t)v * F + c] : 0.f;
    xb[i] = f2bf(val);
}

// ---------------- gather: S[v] = Y[v] + sum_j Y[col[j]]  (unweighted) ----------------
// Lane = (slot, chunk): SLOTS edges at once, CHUNKS lanes x 8 bf16 elems each.
// Cross-slot shfl reduce at end. Output: hi/lo bf16 planes Th, Tl (rows stride KP).
// Row strides XS == KP (zero-padded), both multiples of 32 (64B-aligned rows).

template <int CHUNKS, int SLOTS, int UNR>
__global__ __launch_bounds__(256) void k_gather_s(const unsigned short* __restrict__ Xb,
                                                  const int* __restrict__ rowptr,
                                                  const int* __restrict__ col,
                                                  unsigned short* __restrict__ Th,
                                                  unsigned short* __restrict__ Tl,
                                                  int N, int XS, int KPf) {
    const int v = blockIdx.x * 4 + (threadIdx.x >> 6);
    const int lane = threadIdx.x & 63;
    if (v >= N) return;
    constexpr int VW = 8;
    const int slot = lane / CHUNKS;
    const int chunk = lane - slot * CHUNKS;
    const bool act = lane < CHUNKS * SLOTS;
    const int f0 = chunk * VW;

    float acc[VW];
#pragma unroll
    for (int u = 0; u < VW; u++) acc[u] = 0.f;
    if (slot == 0) {   // self term, coefficient 1
        ushort8v h = *(const ushort8v*)(Xb + (size_t)v * XS + f0);
#pragma unroll
        for (int u = 0; u < VW; u++) acc[u] = bf2f(h[u]);
    }

    const int beg = rowptr[v], end = rowptr[v + 1];
    for (int jb = beg; jb < end; jb += 64) {
        const int nj = min(64, end - jb);
        int ec = 0;
        if (lane < nj) ec = col[jb + lane];
        for (int e = 0; e < nj; e += SLOTS * UNR) {
            int cs[UNR];
            bool vs[UNR];
#pragma unroll
            for (int u = 0; u < UNR; u++) {
                int srcl = e + u * SLOTS + slot;
                vs[u] = act && (srcl < nj);
                cs[u] = __shfl(ec, srcl & 63);
            }
            ushort8v xv[UNR];
#pragma unroll
            for (int u = 0; u < UNR; u++) {
                xv[u] = zero8();
                if (vs[u]) xv[u] = *(const ushort8v*)(Xb + (size_t)cs[u] * XS + f0);
            }
#pragma unroll
            for (int u = 0; u < UNR; u++)
#pragma unroll
                for (int k2 = 0; k2 < VW; k2++)
                    acc[k2] += bf2f(xv[u][k2]);
        }
    }

    // reduce across slots (valid on slot 0)
#pragma unroll
    for (int k2 = 0; k2 < VW; k2++) {
        float t2 = acc[k2];
#pragma unroll
        for (int s2 = 1; s2 < SLOTS; s2++) t2 += __shfl(acc[k2], chunk + s2 * CHUNKS);
        acc[k2] = t2;
    }

    if (slot == 0 && f0 < KPf) {
        ushort8v h8, l8;
#pragma unroll
        for (int u = 0; u < VW; u++) {
            unsigned short hh = f2bf(acc[u]);
            h8[u] = hh;
            l8[u] = f2bf(acc[u] - bf2f(hh));
        }
        *(ushort8v*)(Th + (size_t)v * KPf + f0) = h8;
        *(ushort8v*)(Tl + (size_t)v * KPf + f0) = l8;
    }
}

// ---------------- W preprocess: transpose + split into bf16 hi/lo, k-padded to KP --------

__global__ __launch_bounds__(256) void k_wsplit(const float* __restrict__ W,
                                                unsigned short* __restrict__ Wth,
                                                unsigned short* __restrict__ Wtl,
                                                int K, int Fout, int KP) {
    int i = blockIdx.x * blockDim.x + threadIdx.x;
    if (i >= Fout * KP) return;
    int c = i / KP, k = i - c * KP;
    float w = (k < K) ? W[(size_t)k * Fout + c] : 0.f;
    unsigned short h = f2bf(w);
    Wth[i] = h;
    Wtl[i] = f2bf(w - bf2f(h));
}

// ---------------- split-bf16 MFMA GEMM, B-resident-in-LDS, NO K-loop barriers ----------
// B slab (128 cols x KP, hi+lo) staged once in fragment order -> conflict-free ds_read.
// A streamed from global hi/lo planes straight into MFMA A-frags (64B coalesced rows).
// D = Al*Bh + Ah*Bl + Ah*Bh. X' = relu(dinv[row]*(S@W) + bias).
// MODE 0: store bf16 Y' = dinv[row]*X' (row stride CSbf, pad cols zeroed).
// MODE 1: per-graph max pool of X' via atomicMax (f32 G).

template <int NT, int MODE>
__global__ __launch_bounds__(256) void k_gemm_br(
    const unsigned short* __restrict__ Ah, const unsigned short* __restrict__ Al,
    const unsigned short* __restrict__ Bth, const unsigned short* __restrict__ Btl,
    const float* __restrict__ bias, const float* __restrict__ dinvp,
    unsigned short* __restrict__ Cb, int CSbf,
    const int* __restrict__ batch, float* __restrict__ G,
    int N, int Fout) {
    constexpr int KP = NT * 32;
    constexpr int PL = 8 * NT * 512;             // ushorts per plane
    __shared__ unsigned short sB[2 * PL];        // NT=3: 48KB, NT=5: 80KB
    __shared__ int sBatch[128];

    const int t = threadIdx.x;
    const int r0 = blockIdx.x * 128;
    const int c0 = blockIdx.y * 128;
    const int lane = t & 63;
    const int wv = t >> 6;
    const int l15 = lane & 15;
    const int lg = lane >> 4;

    // ---- stage B slab (both planes), fragment order; ONE barrier ----
    constexpr int KG = KP >> 3;
    for (int i = t; i < 128 * KG; i += 256) {
        int colc = i / KG, kg = i - colc * KG;
        int gc = c0 + colc;
        ushort8v h = zero8(), l = zero8();
        if (gc < Fout) {
            h = *(const ushort8v*)(Bth + (size_t)gc * KP + kg * 8);
            l = *(const ushort8v*)(Btl + (size_t)gc * KP + kg * 8);
        }
        int jt = colc >> 4, tc = kg >> 2, g = kg & 3;
        int off = (jt * NT + tc) * 512 + ((colc & 15) + 16 * g) * 8;
        *(ushort8v*)&sB[off] = h;
        *(ushort8v*)&sB[PL + off] = l;
    }
    if (MODE == 1 && t < 128) sBatch[t] = (r0 + t < N) ? batch[r0 + t] : -1;
    __syncthreads();

    // ---- wave covers 32 rows x 128 cols ----
    const int wrow = wv * 32;
    const int row0 = r0 + wrow + l15;
    const int row1 = row0 + 16;
    const bool ok0 = row0 < N;
    const bool ok1 = row1 < N;
    const unsigned short* a0h = Ah + (size_t)row0 * KP;
    const unsigned short* a0l = Al + (size_t)row0 * KP;
    const unsigned short* a1h = Ah + (size_t)row1 * KP;
    const unsigned short* a1l = Al + (size_t)row1 * KP;

    f32x4 acc[2][8];
#pragma unroll
    for (int i = 0; i < 2; i++)
#pragma unroll
        for (int j = 0; j < 8; j++) acc[i][j] = (f32x4){0.f, 0.f, 0.f, 0.f};

#pragma unroll 2
    for (int tc = 0; tc < NT; ++tc) {
        const int ko = tc * 32 + lg * 8;
        short8v A0h = ok0 ? *(const short8v*)(a0h + ko) : (short8v)zero8();
        short8v A0l = ok0 ? *(const short8v*)(a0l + ko) : (short8v)zero8();
        short8v A1h = ok1 ? *(const short8v*)(a1h + ko) : (short8v)zero8();
        short8v A1l = ok1 ? *(const short8v*)(a1l + ko) : (short8v)zero8();
#pragma unroll
        for (int j = 0; j < 8; j++) {
            const int off = (j * NT + tc) * 512 + lane * 8;
            short8v bh = *(const short8v*)&sB[off];
            short8v bl = *(const short8v*)&sB[PL + off];
            acc[0][j] = __builtin_amdgcn_mfma_f32_16x16x32_bf16(A0l, bh, acc[0][j], 0, 0, 0);
            acc[0][j] = __builtin_amdgcn_mfma_f32_16x16x32_bf16(A0h, bl, acc[0][j], 0, 0, 0);
            acc[0][j] = __builtin_amdgcn_mfma_f32_16x16x32_bf16(A0h, bh, acc[0][j], 0, 0, 0);
            acc[1][j] = __builtin_amdgcn_mfma_f32_16x16x32_bf16(A1l, bh, acc[1][j], 0, 0, 0);
            acc[1][j] = __builtin_amdgcn_mfma_f32_16x16x32_bf16(A1h, bl, acc[1][j], 0, 0, 0);
            acc[1][j] = __builtin_amdgcn_mfma_f32_16x16x32_bf16(A1h, bh, acc[1][j], 0, 0, 0);
        }
    }

    // per-thread row scales (C/D layout m89-verified: col = lane&15, row = (lane>>4)*4 + reg)
    float drw[8];
#pragma unroll
    for (int i = 0; i < 2; i++)
#pragma unroll
        for (int q = 0; q < 4; q++) {
            int gr = r0 + wrow + i * 16 + (lane >> 4) * 4 + q;
            drw[i * 4 + q] = (gr < N) ? dinvp[gr] : 0.f;
        }

    if (MODE == 0) {
#pragma unroll
        for (int j = 0; j < 8; j++) {
            int gc = c0 + j * 16 + l15;
            if (gc >= CSbf) continue;
            float bv = (gc < Fout) ? bias[gc] : 0.f;
#pragma unroll
            for (int i = 0; i < 2; i++) {
                int rb = r0 + wrow + i * 16 + (lane >> 4) * 4;
#pragma unroll
                for (int q = 0; q < 4; q++) {
                    int gr = rb + q;
                    if (gr >= N) continue;
                    float dr = drw[i * 4 + q];
                    float vv = (gc < Fout) ? fmaxf(fmaf(acc[i][j][q], dr, bv), 0.f) * dr : 0.f;
                    Cb[(size_t)gr * CSbf + gc] = f2bf(vv);
                }
            }
        }
    } else {
#pragma unroll
        for (int j = 0; j < 8; j++) {
            int gc = c0 + j * 16 + l15;
            if (gc >= Fout) continue;
            float bv = bias[gc];
            int gcur = -1;
            float vmax = 0.f;
#pragma unroll
            for (int i = 0; i < 2; i++) {
                int lr = wrow + i * 16 + (lane >> 4) * 4;
#pragma unroll
                for (int q = 0; q < 4; q++) {
                    int g = sBatch[lr + q];
                    float vv = fmaxf(fmaf(acc[i][j][q], drw[i * 4 + q], bv), 0.f);
                    if (g < 0) continue;
                    if (g != gcur) {
                        if (gcur >= 0)
                            atomicMax((int*)&G[(size_t)gcur * Fout + gc], __float_as_int(vmax));
                        gcur = g;
                        vmax = vv;
                    } else {
                        vmax = fmaxf(vmax, vv);
                    }
                }
            }
            if (gcur >= 0) atomicMax((int*)&G[(size_t)gcur * Fout + gc], __float_as_int(vmax));
        }
    }
}

// ---------------- fc_g1: C[M,Nout] = relu(A@W + b); 2 rows x 256 cols per block ----------

__global__ __launch_bounds__(256) void k_fc1(const float* __restrict__ A,
                                             const float* __restrict__ W,
                                             const float* __restrict__ bias,
                                             float* __restrict__ C,
                                             int M, int K, int Nout) {
    __shared__ float sA[2 * 304];
    const int t = threadIdx.x;
    const int m0 = blockIdx.x * 2;
    const int oc = blockIdx.y * 256 + t;

    for (int i = t; i < 2 * K; i += 256) {
        int r = i / K, k = i - r * K;
        sA[r * 304 + k] = (m0 + r < M) ? A[(size_t)(m0 + r) * K + k] : 0.f;
    }
    __syncthreads();

    float acc0 = 0.f, acc1 = 0.f;
    int k = 0;
    for (; k + 8 <= K; k += 8) {
        float w[8];
#pragma unroll
        for (int u = 0; u < 8; u++) w[u] = W[(size_t)(k + u) * Nout + oc];
#pragma unroll
        for (int u = 0; u < 8; u++) {
            acc0 = fmaf(sA[k + u], w[u], acc0);
            acc1 = fmaf(sA[304 + k + u], w[u], acc1);
        }
    }
    for (; k < K; k++) {
        float w = W[(size_t)k * Nout + oc];
        acc0 = fmaf(sA[k], w, acc0);
        acc1 = fmaf(sA[304 + k], w, acc1);
    }
    float bv = bias[oc];
    if (m0 < M) C[(size_t)m0 * Nout + oc] = fmaxf(acc0 + bv, 0.f);
    if (m0 + 1 < M) C[(size_t)(m0 + 1) * Nout + oc] = fmaxf(acc1 + bv, 0.f);
}

// ---------------- fc_g2: split-K partial (KS=256) + deterministic reduce ----------------

__global__ __launch_bounds__(256) void k_fc2p(const float* __restrict__ A,
                                              const float* __restrict__ W,
                                              float* __restrict__ P,
                                              int M, int K, int Nout) {
    __shared__ float sA[2 * 256];
    const int t = threadIdx.x;
    const int m0 = blockIdx.x * 2;
    const int sk = blockIdx.y;
    const int k0 = sk * 256;
    const int row = t >> 7;
    const int oc = t & 127;

    for (int i = t; i < 2 * 256; i += 256) {
        int r = i >> 8, k = i & 255;
        sA[i] = (m0 + r < M) ? A[(size_t)(m0 + r) * K + k0 + k] : 0.f;
    }
    __syncthreads();

    const float* a = sA + row * 256;
    float acc = 0.f;
    for (int k = 0; k < 256; k += 8) {
        float w[8];
#pragma unroll
        for (int u = 0; u < 8; u++) w[u] = W[(size_t)(k0 + k + u) * Nout + oc];
#pragma unroll
        for (int u = 0; u < 8; u++) acc = fmaf(a[k + u], w[u], acc);
    }
    int m = m0 + row;
    if (m < M) P[((size_t)sk * M + m) * Nout + oc] = acc;
}

__global__ __launch_bounds__(256) void k_fc2r(const float* __restrict__ P,
                                              const float* __restrict__ bias,
                                              float* __restrict__ C,
                                              int M, int Nout, int SK) {
    int i = blockIdx.x * blockDim.x + threadIdx.x;
    if (i >= M * Nout) return;
    int oc = i % Nout;
    float acc = bias[oc];
    for (int s2 = 0; s2 < SK; s2++) acc += P[(size_t)s2 * M * Nout + i];
    C[i] = acc;
}

// ---------------- launch ----------------

extern "C" void kernel_launch(void* const* d_in, const int* in_sizes, int n_in,
                              void* d_out, int out_size, void* d_ws, size_t ws_size,
                              hipStream_t stream) {
    const float* x     = (const float*)d_in[0];
    const int*   ei    = (const int*)d_in[1];
    const int*   batch = (const int*)d_in[2];
    const float* W1 = (const float*)d_in[3];
    const float* b1 = (const float*)d_in[4];
    const float* W2 = (const float*)d_in[5];
    const float* b2 = (const float*)d_in[6];
    const float* W3 = (const float*)d_in[7];
    const float* b3 = (const float*)d_in[8];
    const float* Wg1 = (const float*)d_in[9];
    const float* bg1 = (const float*)d_in[10];
    const float* Wg2 = (const float*)d_in[11];
    const float* bg2 = (const float*)d_in[12];

    const int N  = in_sizes[2];          // 50000
    const int E  = in_sizes[1] / 2;      // 800000
    const int F1 = in_sizes[4];          // 75
    const int F2 = in_sizes[6];          // 150
    const int F3 = in_sizes[8];          // 300
    const int H1 = in_sizes[10];         // 1024
    const int OC = in_sizes[12];         // 128
    const int NG = out_size / OC;        // 256
    const int FIN = in_sizes[3] / F1;    // 75

    const int KP1 = 96;                  // K=75 padded; all strides = KP (64B-mult rows)
    const int KP3 = 160;                 // K=150 padded

    const int* src = ei;
    const int* dst = ei + E;

    char* base = (char*)d_ws;
    size_t off = 0;
    auto alloc = [&](size_t bytes) -> void* {
        void* p = base + off;
        off = (off + bytes + 255) & ~(size_t)255;
        return p;
    };
    int*   cnt    = (int*)alloc((size_t)N * 4);
    int*   fill   = (int*)alloc((size_t)N * 4);
    int*   rowptr = (int*)alloc((size_t)(N + 1) * 4);
    float* dinv   = (float*)alloc((size_t)N * 4);
    int*   bsum   = (int*)alloc(256 * 4);
    int*   col    = (int*)alloc((size_t)E * 4);
    unsigned short* W1th = (unsigned short*)alloc((size_t)F1 * KP1 * 2);
    unsigned short* W1tl = (unsigned short*)alloc((size_t)F1 * KP1 * 2);
    unsigned short* W2th = (unsigned short*)alloc((size_t)F2 * KP1 * 2);
    unsigned short* W2tl = (unsigned short*)alloc((size_t)F2 * KP1 * 2);
    unsigned short* W3th = (unsigned short*)alloc((size_t)F3 * KP3 * 2);
    unsigned short* W3tl = (unsigned short*)alloc((size_t)F3 * KP3 * 2);
    float* Gb  = (float*)alloc((size_t)NG * F3 * 4);
    float* g1  = (float*)alloc((size_t)NG * H1 * 4);
    float* P2  = (float*)alloc((size_t)4 * NG * OC * 4);                // split-K partials
    unsigned short* TgH = (unsigned short*)alloc((size_t)N * KP3 * 2);  // 16 MB hi plane
    unsigned short* TgL = (unsigned short*)alloc((size_t)N * KP3 * 2);  // 16 MB lo plane
    unsigned short* Xb  = (unsigned short*)alloc((size_t)N * KP1 * 2);  // 9.6 MB scaled x
    unsigned short* H1b = (unsigned short*)alloc((size_t)N * KP1 * 2);  // 9.6 MB Y1
    unsigned short* H2b = (unsigned short*)alloc((size_t)N * KP3 * 2);  // 16 MB Y2

    hipMemsetAsync(cnt, 0, (size_t)N * 4, stream);
    hipMemsetAsync(fill, 0, (size_t)N * 4, stream);
    hipMemsetAsync(Gb, 0, (size_t)NG * F3 * 4, stream);

    // ---- CSR ----
    k_count<<<ceil_div_i(E, 256), 256, 0, stream>>>(dst, E, cnt);
    k_dinv<<<ceil_div_i(N, 256), 256, 0, stream>>>(cnt, dinv, N);
    int NB = ceil_div_i(N, SCAN_B);
    k_scan1<<<NB, 256, 0, stream>>>(cnt, rowptr, bsum, N);
    k_scan2<<<1, 256, 0, stream>>>(bsum, NB);
    k_scan3<<<ceil_div_i(N, 256), 256, 0, stream>>>(rowptr, bsum, N, E);
    k_fill<<<ceil_div_i(E, 256), 256, 0, stream>>>(src, dst, E, rowptr, fill, col);

    // ---- weight splits + scaled-x (small) ----
    k_wsplit<<<ceil_div_i((long long)F1 * KP1, 256), 256, 0, stream>>>(W1, W1th, W1tl, FIN, F1, KP1);
    k_wsplit<<<ceil_div_i((long long)F2 * KP1, 256), 256, 0, stream>>>(W2, W2th, W2tl, F1, F2, KP1);
    k_wsplit<<<ceil_div_i((long long)F3 * KP3, 256), 256, 0, stream>>>(W3, W3th, W3tl, F2, F3, KP3);
    k_xscale<<<ceil_div_i((long long)N * KP1, 256), 256, 0, stream>>>(x, dinv, Xb, N, FIN, KP1);

    dim3 blk(256);
    int gw = ceil_div_i(N, 4);
    int gx = ceil_div_i(N, 128);

    // conv1: gather Xb (12 chunks x 5 slots) -> TgH/TgL stride 96; GEMM K=96, Fout=75
    k_gather_s<12, 5, 2><<<gw, blk, 0, stream>>>(Xb, rowptr, col, TgH, TgL, N, KP1, KP1);
    {
        dim3 g(gx, ceil_div_i(F1, 128));
        k_gemm_br<3, 0><<<g, blk, 0, stream>>>(TgH, TgL, W1th, W1tl, b1, dinv, H1b, KP1,
                                               nullptr, nullptr, N, F1);
    }
    // conv2: gather Y1 -> TgH/TgL stride 96; GEMM K=96, Fout=150 -> Y2 stride 160
    k_gather_s<12, 5, 2><<<gw, blk, 0, stream>>>(H1b, rowptr, col, TgH, TgL, N, KP1, KP1);
    {
        dim3 g(gx, ceil_div_i(F2, 128));
        k_gemm_br<3, 0><<<g, blk, 0, stream>>>(TgH, TgL, W2th, W2tl, b2, dinv, H2b, KP3,
                                               nullptr, nullptr, N, F2);
    }
    // conv3: gather Y2 (20 chunks x 3 slots) -> stride 160; GEMM K=160, fused relu+pool
    k_gather_s<20, 3, 4><<<gw, blk, 0, stream>>>(H2b, rowptr, col, TgH, TgL, N, KP3, KP3);
    {
        dim3 g(gx, ceil_div_i(F3, 128));
        k_gemm_br<5, 1><<<g, blk, 0, stream>>>(TgH, TgL, W3th, W3tl, b3, dinv, nullptr, 0,
                                               batch, Gb, N, F3);
    }

    // fc_g1: 2 rows x 256 cols per block -> grid (128, 4) = 512 blocks
    {
        dim3 g(ceil_div_i(NG, 2), H1 / 256);
        k_fc1<<<g, 256, 0, stream>>>(Gb, Wg1, bg1, g1, NG, F3, H1);
    }
    // fc_g2: split-K=4 partials (512 blocks) + deterministic reduce
    {
        dim3 g(ceil_div_i(NG, 2), 4);
        k_fc2p<<<g, 256, 0, stream>>>(g1, Wg2, P2, NG, H1, OC);
        k_fc2r<<<ceil_div_i((long long)NG * OC, 256), 256, 0, stream>>>(
            P2, bg2, (float*)d_out, NG, OC, 4);
    }
}

// Round 14
// 336.233 us; speedup vs baseline: 1.1279x; 1.1279x over previous
//
#include <hip/hip_runtime.h>
#include <math.h>

#define SCAN_B 1024
#define LDST 40   // LDS row stride in bf16 elems (32 data + 8 pad) — round-11 proven

typedef __attribute__((ext_vector_type(8))) short short8v;
typedef __attribute__((ext_vector_type(8))) unsigned short ushort8v;
typedef __attribute__((ext_vector_type(4))) float f32x4;

static inline int ceil_div_i(long long a, int b) { return (int)((a + b - 1) / b); }

__device__ __forceinline__ unsigned short f2bf(float x) {
    unsigned int u = __float_as_uint(x);
    u += 0x7fffu + ((u >> 16) & 1u);   // round-to-nearest-even
    return (unsigned short)(u >> 16);
}
__device__ __forceinline__ float bf2f(unsigned short h) {
    return __uint_as_float(((unsigned int)h) << 16);
}
__device__ __forceinline__ ushort8v zero8() {
    ushort8v z;
#pragma unroll
    for (int e = 0; e < 8; e++) z[e] = 0;
    return z;
}

// ---------------- CSR construction ----------------

__global__ __launch_bounds__(256) void k_count(const int* __restrict__ dst, int E,
                                               int* __restrict__ cnt) {
    int i = blockIdx.x * blockDim.x + threadIdx.x;
    if (i < E) atomicAdd(&cnt[dst[i]], 1);
}

__global__ __launch_bounds__(256) void k_dinv(const int* __restrict__ cnt,
                                              float* __restrict__ dinv, int N) {
    int i = blockIdx.x * blockDim.x + threadIdx.x;
    if (i < N) dinv[i] = (float)(1.0 / sqrt((double)(cnt[i] + 1)));
}

__global__ __launch_bounds__(256) void k_scan1(const int* __restrict__ cnt,
                                               int* __restrict__ rowptr,
                                               int* __restrict__ bsum, int N) {
    __shared__ int s[256];
    int tid = threadIdx.x;
    int base = blockIdx.x * SCAN_B + tid * 4;
    int a0 = (base + 0 < N) ? cnt[base + 0] : 0;
    int a1 = (base + 1 < N) ? cnt[base + 1] : 0;
    int a2 = (base + 2 < N) ? cnt[base + 2] : 0;
    int a3 = (base + 3 < N) ? cnt[base + 3] : 0;
    int tsum = a0 + a1 + a2 + a3;
    s[tid] = tsum;
    __syncthreads();
    for (int off = 1; off < 256; off <<= 1) {
        int val = 0;
        if (tid >= off) val = s[tid - off];
        __syncthreads();
        if (tid >= off) s[tid] += val;
        __syncthreads();
    }
    int texcl = s[tid] - tsum;
    if (tid == 255) bsum[blockIdx.x] = s[255];
    if (base + 0 < N) rowptr[base + 0] = texcl;
    if (base + 1 < N) rowptr[base + 1] = texcl + a0;
    if (base + 2 < N) rowptr[base + 2] = texcl + a0 + a1;
    if (base + 3 < N) rowptr[base + 3] = texcl + a0 + a1 + a2;
}

__global__ __launch_bounds__(256) void k_scan2(int* __restrict__ bsum, int NB) {
    __shared__ int s[256];
    int tid = threadIdx.x;
    int v = (tid < NB) ? bsum[tid] : 0;
    s[tid] = v;
    __syncthreads();
    for (int off = 1; off < 256; off <<= 1) {
        int val = 0;
        if (tid >= off) val = s[tid - off];
        __syncthreads();
        if (tid >= off) s[tid] += val;
        __syncthreads();
    }
    if (tid < NB) bsum[tid] = s[tid] - v;
}

__global__ __launch_bounds__(256) void k_scan3(int* __restrict__ rowptr,
                                               const int* __restrict__ bsum, int N, int E) {
    int i = blockIdx.x * blockDim.x + threadIdx.x;
    if (i < N) rowptr[i] += bsum[i >> 10];
    if (i == 0) rowptr[N] = E;
}

// fill writes ONLY col (edge weights eliminated algebraically via dinv pre-scaling)
__global__ __launch_bounds__(256) void k_fill(const int* __restrict__ src,
                                              const int* __restrict__ dst, int E,
                                              const int* __restrict__ rowptr,
                                              int* __restrict__ fill,
                                              int* __restrict__ col) {
    int e = blockIdx.x * blockDim.x + threadIdx.x;
    if (e >= E) return;
    int s = src[e], d = dst[e];
    int pos = atomicAdd(&fill[d], 1);
    col[rowptr[d] + pos] = s;
}

// ---------------- scale+pad x -> bf16: Y[v][c] = bf16(dinv[v]*x[v][c]), stride XS ------

__global__ __launch_bounds__(256) void k_xscale(const float* __restrict__ x,
                                                const float* __restrict__ dinv,
                                                unsigned short* __restrict__ xb,
                                                int N, int F, int XS) {
    int i = blockIdx.x * blockDim.x + threadIdx.x;
    int v = i / XS, c = i - v * XS;
    if (v >= N) return;
    float val = (c < F) ? dinv[v] * x[(size_t)v * F + c] : 0.f;
    xb[i] = f2bf(val);
}

// ---------------- gather: S[v] = Y[v] + sum_j Y[col[j]]  (unweighted) ----------------
// Lane = (slot, chunk): SLOTS edges at once, CHUNKS lanes x 8 bf16 elems each.
// Cross-slot shfl reduce at end. X rows bf16 stride XS; T f32 rows stride KPf.

template <int CHUNKS, int SLOTS, int UNR>
__global__ __launch_bounds__(256) void k_gather_s(const unsigned short* __restrict__ Xb,
                                                  const int* __restrict__ rowptr,
                                                  const int* __restrict__ col,
                                                  float* __restrict__ T, int N,
                                                  int XS, int KPf) {
    const int v = blockIdx.x * 4 + (threadIdx.x >> 6);
    const int lane = threadIdx.x & 63;
    if (v >= N) return;
    constexpr int VW = 8;
    const int slot = lane / CHUNKS;
    const int chunk = lane - slot * CHUNKS;
    const bool act = lane < CHUNKS * SLOTS;
    const int f0 = chunk * VW;

    float acc[VW];
#pragma unroll
    for (int u = 0; u < VW; u++) acc[u] = 0.f;
    if (slot == 0) {   // self term, coefficient 1
        ushort8v h = *(const ushort8v*)(Xb + (size_t)v * XS + f0);
#pragma unroll
        for (int u = 0; u < VW; u++) acc[u] = bf2f(h[u]);
    }

    const int beg = rowptr[v], end = rowptr[v + 1];
    for (int jb = beg; jb < end; jb += 64) {
        const int nj = min(64, end - jb);
        int ec = 0;
        if (lane < nj) ec = col[jb + lane];
        for (int e = 0; e < nj; e += SLOTS * UNR) {
            int cs[UNR];
            bool vs[UNR];
#pragma unroll
            for (int u = 0; u < UNR; u++) {
                int srcl = e + u * SLOTS + slot;
                vs[u] = act && (srcl < nj);
                cs[u] = __shfl(ec, srcl & 63);
            }
            ushort8v xv[UNR];
#pragma unroll
            for (int u = 0; u < UNR; u++) {
                xv[u] = zero8();
                if (vs[u]) xv[u] = *(const ushort8v*)(Xb + (size_t)cs[u] * XS + f0);
            }
#pragma unroll
            for (int u = 0; u < UNR; u++)
#pragma unroll
                for (int k2 = 0; k2 < VW; k2++)
                    acc[k2] += bf2f(xv[u][k2]);
        }
    }

    // reduce across slots (valid on slot 0)
#pragma unroll
    for (int k2 = 0; k2 < VW; k2++) {
        float t2 = acc[k2];
#pragma unroll
        for (int s2 = 1; s2 < SLOTS; s2++) t2 += __shfl(acc[k2], chunk + s2 * CHUNKS);
        acc[k2] = t2;
    }

    if (slot == 0 && f0 < KPf) {
        float* tv = T + (size_t)v * KPf + f0;
        f32x4 o0 = {acc[0], acc[1], acc[2], acc[3]};
        f32x4 o1 = {acc[4], acc[5], acc[6], acc[7]};
        *(f32x4*)tv = o0;
        *(f32x4*)(tv + 4) = o1;
    }
}

// ---------------- W preprocess: transpose + split into bf16 hi/lo, k-padded to KP --------

__global__ __launch_bounds__(256) void k_wsplit(const float* __restrict__ W,
                                                unsigned short* __restrict__ Wth,
                                                unsigned short* __restrict__ Wtl,
                                                int K, int Fout, int KP) {
    int i = blockIdx.x * blockDim.x + threadIdx.x;
    if (i >= Fout * KP) return;
    int c = i / KP, k = i - c * KP;
    float w = (k < K) ? W[(size_t)k * Fout + c] : 0.f;
    unsigned short h = f2bf(w);
    Wth[i] = h;
    Wtl[i] = f2bf(w - bf2f(h));
}

// ---------------- split-bf16 MFMA GEMM with row scaling (round-11 structure) ----------
// 128-row x CT-col tile (CT = 32*NJW), 4 waves 2x2, wave = 4 x NJW tiles of 16x16x32.
// D = Al*Bh + Ah*Bl + Ah*Bh. A split on the fly from f32. X' = relu(dinv[row]*(S@W)+bias).
// MODE 0: store bf16 Y' = dinv[row]*X' (row stride CSbf, pad cols zeroed).
// MODE 1: per-graph max pool of X' via atomicMax (f32 G).

template <int NJW, int MODE>
__global__ __launch_bounds__(256) void k_gemm_mfma(
    const float* __restrict__ A, int KPf,
    const unsigned short* __restrict__ Bth, const unsigned short* __restrict__ Btl,
    const float* __restrict__ bias, const float* __restrict__ dinvp,
    unsigned short* __restrict__ Cb, int CSbf,
    const int* __restrict__ batch, float* __restrict__ G,
    int N, int KP, int Fout) {
    constexpr int CT = 32 * NJW;                 // 96 or 160
    constexpr int BIT = (2 * CT + 255) / 256;    // B staging iterations (1 or 2)
    __shared__ unsigned short sAh[128 * LDST];
    __shared__ unsigned short sAl[128 * LDST];
    __shared__ unsigned short sBh[CT * LDST];
    __shared__ unsigned short sBl[CT * LDST];
    __shared__ int sBatch[128];

    const int t = threadIdx.x;
    const int r0 = blockIdx.x * 128;
    const int c0 = blockIdx.y * CT;
    const int lane = t & 63;
    const int wv = t >> 6;
    const int wrow = (wv >> 1) * 64;
    const int wcol = (wv & 1) * (16 * NJW);
    const int l15 = lane & 15;
    const int lk = (lane >> 4) * 8;
    const int nt = KP >> 5;

    const int srow = t >> 1;
    const int sseg = (t & 1) << 4;

    if (MODE == 1 && t < 128) sBatch[t] = (r0 + t < N) ? batch[r0 + t] : -1;

    const bool arow_ok = (r0 + srow) < N;
    const float* aRow = A + (size_t)(r0 + srow) * KPf;

    float av[16];
    ushort8v rbh[BIT][2], rbl[BIT][2];

    auto gload = [&](int kk) {
#pragma unroll
        for (int u = 0; u < 4; u++) {
            int gk = kk + sseg + u * 4;
            f32x4 f = {0.f, 0.f, 0.f, 0.f};
            if (arow_ok && gk < KPf) f = *(const f32x4*)&aRow[gk];
#pragma unroll
            for (int e = 0; e < 4; e++) av[u * 4 + e] = f[e];
        }
#pragma unroll
        for (int it = 0; it < BIT; it++) {
            int item = it * 256 + t;
            int brow = item >> 1;
            int bseg = (item & 1) << 4;
            rbh[it][0] = zero8(); rbh[it][1] = zero8();
            rbl[it][0] = zero8(); rbl[it][1] = zero8();
            if (brow < CT) {
                int gc = c0 + brow;
                if (gc < Fout) {
                    const unsigned short* bh = Bth + (size_t)gc * KP + kk + bseg;
                    const unsigned short* bl = Btl + (size_t)gc * KP + kk + bseg;
                    rbh[it][0] = *(const ushort8v*)bh;
                    rbh[it][1] = *(const ushort8v*)(bh + 8);
                    rbl[it][0] = *(const ushort8v*)bl;
                    rbl[it][1] = *(const ushort8v*)(bl + 8);
                }
            }
        }
    };

    auto wlds = [&]() {
        int off = srow * LDST + sseg;
        ushort8v h0, h1, l0, l1;
#pragma unroll
        for (int e = 0; e < 8; e++) {
            unsigned short hh = f2bf(av[e]);
            h0[e] = hh;
            l0[e] = f2bf(av[e] - bf2f(hh));
        }
#pragma unroll
        for (int e = 0; e < 8; e++) {
            unsigned short hh = f2bf(av[8 + e]);
            h1[e] = hh;
            l1[e] = f2bf(av[8 + e] - bf2f(hh));
        }
        *(ushort8v*)&sAh[off] = h0;
        *(ushort8v*)&sAh[off + 8] = h1;
        *(ushort8v*)&sAl[off] = l0;
        *(ushort8v*)&sAl[off + 8] = l1;
#pragma unroll
        for (int it = 0; it < BIT; it++) {
            int item = it * 256 + t;
            int brow = item >> 1;
            int bseg = (item & 1) << 4;
            if (brow < CT) {
                int boff = brow * LDST + bseg;
                *(ushort8v*)&sBh[boff] = rbh[it][0];
                *(ushort8v*)&sBh[boff + 8] = rbh[it][1];
                *(ushort8v*)&sBl[boff] = rbl[it][0];
                *(ushort8v*)&sBl[boff + 8] = rbl[it][1];
            }
        }
    };

    f32x4 acc[4][NJW];
#pragma unroll
    for (int i = 0; i < 4; i++)
#pragma unroll
        for (int j = 0; j < NJW; j++) acc[i][j] = (f32x4){0.f, 0.f, 0.f, 0.f};

    gload(0);
    for (int tc = 0; tc < nt; ++tc) {
        wlds();
        __syncthreads();
        if (tc + 1 < nt) gload((tc + 1) * 32);   // latency hides under MFMA below
        short8v ah[4], al[4];
#pragma unroll
        for (int i = 0; i < 4; i++) {
            int ro = (wrow + i * 16 + l15) * LDST + lk;
            ah[i] = *(const short8v*)&sAh[ro];
            al[i] = *(const short8v*)&sAl[ro];
        }
#pragma unroll
        for (int j = 0; j < NJW; j++) {
            int co = (wcol + j * 16 + l15) * LDST + lk;
            short8v bh = *(const short8v*)&sBh[co];
            short8v bl = *(const short8v*)&sBl[co];
#pragma unroll
            for (int i = 0; i < 4; i++) {
                acc[i][j] = __builtin_amdgcn_mfma_f32_16x16x32_bf16(al[i], bh, acc[i][j], 0, 0, 0);
                acc[i][j] = __builtin_amdgcn_mfma_f32_16x16x32_bf16(ah[i], bl, acc[i][j], 0, 0, 0);
                acc[i][j] = __builtin_amdgcn_mfma_f32_16x16x32_bf16(ah[i], bh, acc[i][j], 0, 0, 0);
            }
        }
        __syncthreads();
    }

    // per-thread row scales (C/D layout m89-verified: col = lane&15, row = (lane>>4)*4 + reg)
    float drw[16];
#pragma unroll
    for (int i = 0; i < 4; i++)
#pragma unroll
        for (int q = 0; q < 4; q++) {
            int gr = r0 + wrow + i * 16 + (lane >> 4) * 4 + q;
            drw[i * 4 + q] = (gr < N) ? dinvp[gr] : 0.f;
        }

    if (MODE == 0) {
#pragma unroll
        for (int j = 0; j < NJW; j++) {
            int gc = c0 + wcol + j * 16 + l15;
            if (gc >= CSbf) continue;
            float bv = (gc < Fout) ? bias[gc] : 0.f;
#pragma unroll
            for (int i = 0; i < 4; i++) {
                int rb = r0 + wrow + i * 16 + (lane >> 4) * 4;
#pragma unroll
                for (int q = 0; q < 4; q++) {
                    int gr = rb + q;
                    if (gr >= N) continue;
                    float dr = drw[i * 4 + q];
                    float vv = (gc < Fout) ? fmaxf(fmaf(acc[i][j][q], dr, bv), 0.f) * dr : 0.f;
                    Cb[(size_t)gr * CSbf + gc] = f2bf(vv);
                }
            }
        }
    } else {
#pragma unroll
        for (int j = 0; j < NJW; j++) {
            int gc = c0 + wcol + j * 16 + l15;
            if (gc >= Fout) continue;
            float bv = bias[gc];
            int gcur = -1;
            float vmax = 0.f;
#pragma unroll
            for (int i = 0; i < 4; i++) {
                int lr = wrow + i * 16 + (lane >> 4) * 4;
#pragma unroll
                for (int q = 0; q < 4; q++) {
                    int g = sBatch[lr + q];
                    float vv = fmaxf(fmaf(acc[i][j][q], drw[i * 4 + q], bv), 0.f);
                    if (g < 0) continue;
                    if (g != gcur) {
                        if (gcur >= 0)
                            atomicMax((int*)&G[(size_t)gcur * Fout + gc], __float_as_int(vmax));
                        gcur = g;
                        vmax = vv;
                    } else {
                        vmax = fmaxf(vmax, vv);
                    }
                }
            }
            if (gcur >= 0) atomicMax((int*)&G[(size_t)gcur * Fout + gc], __float_as_int(vmax));
        }
    }
}

// ---------------- fc_g1: C[M,Nout] = relu(A@W + b); 2 rows x 256 cols per block ----------

__global__ __launch_bounds__(256) void k_fc1(const float* __restrict__ A,
                                             const float* __restrict__ W,
                                             const float* __restrict__ bias,
                                             float* __restrict__ C,
                                             int M, int K, int Nout) {
    __shared__ float sA[2 * 304];
    const int t = threadIdx.x;
    const int m0 = blockIdx.x * 2;
    const int oc = blockIdx.y * 256 + t;

    for (int i = t; i < 2 * K; i += 256) {
        int r = i / K, k = i - r * K;
        sA[r * 304 + k] = (m0 + r < M) ? A[(size_t)(m0 + r) * K + k] : 0.f;
    }
    __syncthreads();

    float acc0 = 0.f, acc1 = 0.f;
    int k = 0;
    for (; k + 8 <= K; k += 8) {
        float w[8];
#pragma unroll
        for (int u = 0; u < 8; u++) w[u] = W[(size_t)(k + u) * Nout + oc];
#pragma unroll
        for (int u = 0; u < 8; u++) {
            acc0 = fmaf(sA[k + u], w[u], acc0);
            acc1 = fmaf(sA[304 + k + u], w[u], acc1);
        }
    }
    for (; k < K; k++) {
        float w = W[(size_t)k * Nout + oc];
        acc0 = fmaf(sA[k], w, acc0);
        acc1 = fmaf(sA[304 + k], w, acc1);
    }
    float bv = bias[oc];
    if (m0 < M) C[(size_t)m0 * Nout + oc] = fmaxf(acc0 + bv, 0.f);
    if (m0 + 1 < M) C[(size_t)(m0 + 1) * Nout + oc] = fmaxf(acc1 + bv, 0.f);
}

// ---------------- fc_g2: split-K partial (KS=256) + deterministic reduce ----------------

__global__ __launch_bounds__(256) void k_fc2p(const float* __restrict__ A,
                                              const float* __restrict__ W,
                                              float* __restrict__ P,
                                              int M, int K, int Nout) {
    __shared__ float sA[2 * 256];
    const int t = threadIdx.x;
    const int m0 = blockIdx.x * 2;
    const int sk = blockIdx.y;
    const int k0 = sk * 256;
    const int row = t >> 7;
    const int oc = t & 127;

    for (int i = t; i < 2 * 256; i += 256) {
        int r = i >> 8, k = i & 255;
        sA[i] = (m0 + r < M) ? A[(size_t)(m0 + r) * K + k0 + k] : 0.f;
    }
    __syncthreads();

    const float* a = sA + row * 256;
    float acc = 0.f;
    for (int k = 0; k < 256; k += 8) {
        float w[8];
#pragma unroll
        for (int u = 0; u < 8; u++) w[u] = W[(size_t)(k0 + k + u) * Nout + oc];
#pragma unroll
        for (int u = 0; u < 8; u++) acc = fmaf(a[k + u], w[u], acc);
    }
    int m = m0 + row;
    if (m < M) P[((size_t)sk * M + m) * Nout + oc] = acc;
}

__global__ __launch_bounds__(256) void k_fc2r(const float* __restrict__ P,
                                              const float* __restrict__ bias,
                                              float* __restrict__ C,
                                              int M, int Nout, int SK) {
    int i = blockIdx.x * blockDim.x + threadIdx.x;
    if (i >= M * Nout) return;
    int oc = i % Nout;
    float acc = bias[oc];
    for (int s2 = 0; s2 < SK; s2++) acc += P[(size_t)s2 * M * Nout + i];
    C[i] = acc;
}

// ---------------- launch ----------------

extern "C" void kernel_launch(void* const* d_in, const int* in_sizes, int n_in,
                              void* d_out, int out_size, void* d_ws, size_t ws_size,
                              hipStream_t stream) {
    const float* x     = (const float*)d_in[0];
    const int*   ei    = (const int*)d_in[1];
    const int*   batch = (const int*)d_in[2];
    const float* W1 = (const float*)d_in[3];
    const float* b1 = (const float*)d_in[4];
    const float* W2 = (const float*)d_in[5];
    const float* b2 = (const float*)d_in[6];
    const float* W3 = (const float*)d_in[7];
    const float* b3 = (const float*)d_in[8];
    const float* Wg1 = (const float*)d_in[9];
    const float* bg1 = (const float*)d_in[10];
    const float* Wg2 = (const float*)d_in[11];
    const float* bg2 = (const float*)d_in[12];

    const int N  = in_sizes[2];          // 50000
    const int E  = in_sizes[1] / 2;      // 800000
    const int F1 = in_sizes[4];          // 75
    const int F2 = in_sizes[6];          // 150
    const int F3 = in_sizes[8];          // 300
    const int H1 = in_sizes[10];         // 1024
    const int OC = in_sizes[12];         // 128
    const int NG = out_size / OC;        // 256
    const int FIN = in_sizes[3] / F1;    // 75

    const int KP1 = 96,  KPf1 = 80;      // K=75 padded (GEMM loop / A stride)
    const int KP3 = 160, KPf3 = 152;     // K=150 padded
    const int XS0 = 80;                  // x bf16 (pre-scaled) row stride
    const int HS1 = 80;                  // Y1 bf16 row stride
    const int HS2 = 152;                 // Y2 bf16 row stride

    const int* src = ei;
    const int* dst = ei + E;

    char* base = (char*)d_ws;
    size_t off = 0;
    auto alloc = [&](size_t bytes) -> void* {
        void* p = base + off;
        off = (off + bytes + 255) & ~(size_t)255;
        return p;
    };
    int*   cnt    = (int*)alloc((size_t)N * 4);
    int*   fill   = (int*)alloc((size_t)N * 4);
    int*   rowptr = (int*)alloc((size_t)(N + 1) * 4);
    float* dinv   = (float*)alloc((size_t)N * 4);
    int*   bsum   = (int*)alloc(256 * 4);
    int*   col    = (int*)alloc((size_t)E * 4);
    unsigned short* W1th = (unsigned short*)alloc((size_t)F1 * KP1 * 2);
    unsigned short* W1tl = (unsigned short*)alloc((size_t)F1 * KP1 * 2);
    unsigned short* W2th = (unsigned short*)alloc((size_t)F2 * KP1 * 2);
    unsigned short* W2tl = (unsigned short*)alloc((size_t)F2 * KP1 * 2);
    unsigned short* W3th = (unsigned short*)alloc((size_t)F3 * KP3 * 2);
    unsigned short* W3tl = (unsigned short*)alloc((size_t)F3 * KP3 * 2);
    float* Gb  = (float*)alloc((size_t)NG * F3 * 4);
    float* g1  = (float*)alloc((size_t)NG * H1 * 4);
    float* P2  = (float*)alloc((size_t)4 * NG * OC * 4);                // split-K partials
    float* Tg  = (float*)alloc((size_t)N * KPf3 * 4);                   // 30.4 MB
    unsigned short* Xb  = (unsigned short*)alloc((size_t)N * XS0 * 2);  // 8 MB bf16 scaled x
    unsigned short* H1b = (unsigned short*)alloc((size_t)N * HS1 * 2);  // 8 MB bf16
    unsigned short* H2b = (unsigned short*)alloc((size_t)N * HS2 * 2);  // 15.2 MB bf16

    hipMemsetAsync(cnt, 0, (size_t)N * 4, stream);
    hipMemsetAsync(fill, 0, (size_t)N * 4, stream);
    hipMemsetAsync(Gb, 0, (size_t)NG * F3 * 4, stream);

    // ---- CSR ----
    k_count<<<ceil_div_i(E, 256), 256, 0, stream>>>(dst, E, cnt);
    k_dinv<<<ceil_div_i(N, 256), 256, 0, stream>>>(cnt, dinv, N);
    int NB = ceil_div_i(N, SCAN_B);
    k_scan1<<<NB, 256, 0, stream>>>(cnt, rowptr, bsum, N);
    k_scan2<<<1, 256, 0, stream>>>(bsum, NB);
    k_scan3<<<ceil_div_i(N, 256), 256, 0, stream>>>(rowptr, bsum, N, E);
    k_fill<<<ceil_div_i(E, 256), 256, 0, stream>>>(src, dst, E, rowptr, fill, col);

    // ---- weight splits + scaled-x (small) ----
    k_wsplit<<<ceil_div_i((long long)F1 * KP1, 256), 256, 0, stream>>>(W1, W1th, W1tl, FIN, F1, KP1);
    k_wsplit<<<ceil_div_i((long long)F2 * KP1, 256), 256, 0, stream>>>(W2, W2th, W2tl, F1, F2, KP1);
    k_wsplit<<<ceil_div_i((long long)F3 * KP3, 256), 256, 0, stream>>>(W3, W3th, W3tl, F2, F3, KP3);
    k_xscale<<<ceil_div_i((long long)N * XS0, 256), 256, 0, stream>>>(x, dinv, Xb, N, FIN, XS0);

    dim3 blk(256);
    int gw = ceil_div_i(N, 4);
    int gx = ceil_div_i(N, 128);

    // conv1: gather Xb (10 chunks x 6 slots) -> Tg stride 80; GEMM CT=96 covers 75 cols
    k_gather_s<10, 6, 2><<<gw, blk, 0, stream>>>(Xb, rowptr, col, Tg, N, XS0, KPf1);
    {
        dim3 g(gx, 1);
        k_gemm_mfma<3, 0><<<g, blk, 0, stream>>>(Tg, KPf1, W1th, W1tl, b1, dinv, H1b, HS1,
                                                 nullptr, nullptr, N, KP1, F1);
    }
    // conv2: gather Y1 -> Tg stride 80; GEMM CT=160 covers 150 cols
    k_gather_s<10, 6, 2><<<gw, blk, 0, stream>>>(H1b, rowptr, col, Tg, N, HS1, KPf1);
    {
        dim3 g(gx, 1);
        k_gemm_mfma<5, 0><<<g, blk, 0, stream>>>(Tg, KPf1, W2th, W2tl, b2, dinv, H2b, HS2,
                                                 nullptr, nullptr, N, KP1, F2);
    }
    // conv3: gather Y2 (19 chunks x 3 slots) -> Tg stride 152; GEMM CT=160 x2, fused pool
    k_gather_s<19, 3, 4><<<gw, blk, 0, stream>>>(H2b, rowptr, col, Tg, N, HS2, KPf3);
    {
        dim3 g(gx, 2);
        k_gemm_mfma<5, 1><<<g, blk, 0, stream>>>(Tg, KPf3, W3th, W3tl, b3, dinv, nullptr, 0,
                                                 batch, Gb, N, KP3, F3);
    }

    // fc_g1: 2 rows x 256 cols per block -> grid (128, 4) = 512 blocks
    {
        dim3 g(ceil_div_i(NG, 2), H1 / 256);
        k_fc1<<<g, 256, 0, stream>>>(Gb, Wg1, bg1, g1, NG, F3, H1);
    }
    // fc_g2: split-K=4 partials (512 blocks) + deterministic reduce
    {
        dim3 g(ceil_div_i(NG, 2), 4);
        k_fc2p<<<g, 256, 0, stream>>>(g1, Wg2, P2, NG, H1, OC);
        k_fc2r<<<ceil_div_i((long long)NG * OC, 256), 256, 0, stream>>>(
            P2, bg2, (float*)d_out, NG, OC, 4);
    }
}

// Round 15
// 335.763 us; speedup vs baseline: 1.1295x; 1.0014x over previous
//
#include <hip/hip_runtime.h>
#include <math.h>

#define SCAN_B 1024
#define LDST 40   // LDS row stride in bf16 elems (32 data + 8 pad) — round-11 proven

typedef __attribute__((ext_vector_type(8))) short short8v;
typedef __attribute__((ext_vector_type(8))) unsigned short ushort8v;
typedef __attribute__((ext_vector_type(4))) float f32x4;

static inline int ceil_div_i(long long a, int b) { return (int)((a + b - 1) / b); }

__device__ __forceinline__ unsigned short f2bf(float x) {
    unsigned int u = __float_as_uint(x);
    u += 0x7fffu + ((u >> 16) & 1u);   // round-to-nearest-even
    return (unsigned short)(u >> 16);
}
__device__ __forceinline__ float bf2f(unsigned short h) {
    return __uint_as_float(((unsigned int)h) << 16);
}
__device__ __forceinline__ ushort8v zero8() {
    ushort8v z;
#pragma unroll
    for (int e = 0; e < 8; e++) z[e] = 0;
    return z;
}

// ---------------- CSR construction ----------------

__global__ __launch_bounds__(256) void k_count(const int* __restrict__ dst, int E,
                                               int* __restrict__ cnt) {
    int i = blockIdx.x * blockDim.x + threadIdx.x;
    if (i < E) atomicAdd(&cnt[dst[i]], 1);
}

__global__ __launch_bounds__(256) void k_dinv(const int* __restrict__ cnt,
                                              float* __restrict__ dinv, int N) {
    int i = blockIdx.x * blockDim.x + threadIdx.x;
    if (i < N) dinv[i] = (float)(1.0 / sqrt((double)(cnt[i] + 1)));
}

__global__ __launch_bounds__(256) void k_scan1(const int* __restrict__ cnt,
                                               int* __restrict__ rowptr,
                                               int* __restrict__ bsum, int N) {
    __shared__ int s[256];
    int tid = threadIdx.x;
    int base = blockIdx.x * SCAN_B + tid * 4;
    int a0 = (base + 0 < N) ? cnt[base + 0] : 0;
    int a1 = (base + 1 < N) ? cnt[base + 1] : 0;
    int a2 = (base + 2 < N) ? cnt[base + 2] : 0;
    int a3 = (base + 3 < N) ? cnt[base + 3] : 0;
    int tsum = a0 + a1 + a2 + a3;
    s[tid] = tsum;
    __syncthreads();
    for (int off = 1; off < 256; off <<= 1) {
        int val = 0;
        if (tid >= off) val = s[tid - off];
        __syncthreads();
        if (tid >= off) s[tid] += val;
        __syncthreads();
    }
    int texcl = s[tid] - tsum;
    if (tid == 255) bsum[blockIdx.x] = s[255];
    if (base + 0 < N) rowptr[base + 0] = texcl;
    if (base + 1 < N) rowptr[base + 1] = texcl + a0;
    if (base + 2 < N) rowptr[base + 2] = texcl + a0 + a1;
    if (base + 3 < N) rowptr[base + 3] = texcl + a0 + a1 + a2;
}

__global__ __launch_bounds__(256) void k_scan2(int* __restrict__ bsum, int NB) {
    __shared__ int s[256];
    int tid = threadIdx.x;
    int v = (tid < NB) ? bsum[tid] : 0;
    s[tid] = v;
    __syncthreads();
    for (int off = 1; off < 256; off <<= 1) {
        int val = 0;
        if (tid >= off) val = s[tid - off];
        __syncthreads();
        if (tid >= off) s[tid] += val;
        __syncthreads();
    }
    if (tid < NB) bsum[tid] = s[tid] - v;
}

__global__ __launch_bounds__(256) void k_scan3(int* __restrict__ rowptr,
                                               const int* __restrict__ bsum, int N, int E) {
    int i = blockIdx.x * blockDim.x + threadIdx.x;
    if (i < N) rowptr[i] += bsum[i >> 10];
    if (i == 0) rowptr[N] = E;
}

// fill writes ONLY col (edge weights eliminated algebraically via dinv pre-scaling)
__global__ __launch_bounds__(256) void k_fill(const int* __restrict__ src,
                                              const int* __restrict__ dst, int E,
                                              const int* __restrict__ rowptr,
                                              int* __restrict__ fill,
                                              int* __restrict__ col) {
    int e = blockIdx.x * blockDim.x + threadIdx.x;
    if (e >= E) return;
    int s = src[e], d = dst[e];
    int pos = atomicAdd(&fill[d], 1);
    col[rowptr[d] + pos] = s;
}

// ---------------- scale+pad x -> bf16: Y[v][c] = bf16(dinv[v]*x[v][c]), stride XS ------

__global__ __launch_bounds__(256) void k_xscale(const float* __restrict__ x,
                                                const float* __restrict__ dinv,
                                                unsigned short* __restrict__ xb,
                                                int N, int F, int XS) {
    int i = blockIdx.x * blockDim.x + threadIdx.x;
    int v = i / XS, c = i - v * XS;
    if (v >= N) return;
    float val = (c < F) ? dinv[v] * x[(size_t)v * F + c] : 0.f;
    xb[i] = f2bf(val);
}

// ---------------- gather: S[v] = Y[v] + sum_j Y[col[j]]  (unweighted) ----------------
// Lane = (slot, chunk): SLOTS edges at once, CHUNKS lanes x 8 bf16 elems each.
// Cross-slot shfl reduce at end. Output: hi/lo bf16 planes Th, Tl (rows stride KPf).

template <int CHUNKS, int SLOTS, int UNR>
__global__ __launch_bounds__(256) void k_gather_s(const unsigned short* __restrict__ Xb,
                                                  const int* __restrict__ rowptr,
                                                  const int* __restrict__ col,
                                                  unsigned short* __restrict__ Th,
                                                  unsigned short* __restrict__ Tl,
                                                  int N, int XS, int KPf) {
    const int v = blockIdx.x * 4 + (threadIdx.x >> 6);
    const int lane = threadIdx.x & 63;
    if (v >= N) return;
    constexpr int VW = 8;
    const int slot = lane / CHUNKS;
    const int chunk = lane - slot * CHUNKS;
    const bool act = lane < CHUNKS * SLOTS;
    const int f0 = chunk * VW;

    float acc[VW];
#pragma unroll
    for (int u = 0; u < VW; u++) acc[u] = 0.f;
    if (slot == 0) {   // self term, coefficient 1
        ushort8v h = *(const ushort8v*)(Xb + (size_t)v * XS + f0);
#pragma unroll
        for (int u = 0; u < VW; u++) acc[u] = bf2f(h[u]);
    }

    const int beg = rowptr[v], end = rowptr[v + 1];
    for (int jb = beg; jb < end; jb += 64) {
        const int nj = min(64, end - jb);
        int ec = 0;
        if (lane < nj) ec = col[jb + lane];
        for (int e = 0; e < nj; e += SLOTS * UNR) {
            int cs[UNR];
            bool vs[UNR];
#pragma unroll
            for (int u = 0; u < UNR; u++) {
                int srcl = e + u * SLOTS + slot;
                vs[u] = act && (srcl < nj);
                cs[u] = __shfl(ec, srcl & 63);
            }
            ushort8v xv[UNR];
#pragma unroll
            for (int u = 0; u < UNR; u++) {
                xv[u] = zero8();
                if (vs[u]) xv[u] = *(const ushort8v*)(Xb + (size_t)cs[u] * XS + f0);
            }
#pragma unroll
            for (int u = 0; u < UNR; u++)
#pragma unroll
                for (int k2 = 0; k2 < VW; k2++)
                    acc[k2] += bf2f(xv[u][k2]);
        }
    }

    // reduce across slots (valid on slot 0)
#pragma unroll
    for (int k2 = 0; k2 < VW; k2++) {
        float t2 = acc[k2];
#pragma unroll
        for (int s2 = 1; s2 < SLOTS; s2++) t2 += __shfl(acc[k2], chunk + s2 * CHUNKS);
        acc[k2] = t2;
    }

    if (slot == 0 && f0 < KPf) {
        ushort8v h8, l8;
#pragma unroll
        for (int u = 0; u < VW; u++) {
            unsigned short hh = f2bf(acc[u]);
            h8[u] = hh;
            l8[u] = f2bf(acc[u] - bf2f(hh));
        }
        *(ushort8v*)(Th + (size_t)v * KPf + f0) = h8;   // pad lanes write exact zeros
        *(ushort8v*)(Tl + (size_t)v * KPf + f0) = l8;
    }
}

// ---------------- W preprocess: transpose + split into bf16 hi/lo, k-padded to KP --------

__global__ __launch_bounds__(256) void k_wsplit(const float* __restrict__ W,
                                                unsigned short* __restrict__ Wth,
                                                unsigned short* __restrict__ Wtl,
                                                int K, int Fout, int KP) {
    int i = blockIdx.x * blockDim.x + threadIdx.x;
    if (i >= Fout * KP) return;
    int c = i / KP, k = i - c * KP;
    float w = (k < K) ? W[(size_t)k * Fout + c] : 0.f;
    unsigned short h = f2bf(w);
    Wth[i] = h;
    Wtl[i] = f2bf(w - bf2f(h));
}

// ---------------- split-bf16 MFMA GEMM with row scaling (round-14 structure, plane-A) ----
// 128-row x CT-col tile (CT = 32*NJW), 4 waves 2x2, wave = 4 x NJW tiles of 16x16x32.
// A pre-split bf16 hi/lo planes (split done in gather) -> staging is pure reg->LDS copy.
// D = Al*Bh + Ah*Bl + Ah*Bh. X' = relu(dinv[row]*(S@W)+bias).
// MODE 0: store bf16 Y' = dinv[row]*X' (row stride CSbf, pad cols zeroed).
// MODE 1: per-graph max pool of X' via atomicMax (f32 G).

template <int NJW, int MODE>
__global__ __launch_bounds__(256) void k_gemm_mfma(
    const unsigned short* __restrict__ Ahp, const unsigned short* __restrict__ Alp, int KPf,
    const unsigned short* __restrict__ Bth, const unsigned short* __restrict__ Btl,
    const float* __restrict__ bias, const float* __restrict__ dinvp,
    unsigned short* __restrict__ Cb, int CSbf,
    const int* __restrict__ batch, float* __restrict__ G,
    int N, int KP, int Fout) {
    constexpr int CT = 32 * NJW;                 // 96 or 160
    constexpr int BIT = (2 * CT + 255) / 256;    // B staging iterations (1 or 2)
    __shared__ unsigned short sAh[128 * LDST];
    __shared__ unsigned short sAl[128 * LDST];
    __shared__ unsigned short sBh[CT * LDST];
    __shared__ unsigned short sBl[CT * LDST];
    __shared__ int sBatch[128];

    const int t = threadIdx.x;
    const int r0 = blockIdx.x * 128;
    const int c0 = blockIdx.y * CT;
    const int lane = t & 63;
    const int wv = t >> 6;
    const int wrow = (wv >> 1) * 64;
    const int wcol = (wv & 1) * (16 * NJW);
    const int l15 = lane & 15;
    const int lk = (lane >> 4) * 8;
    const int nt = KP >> 5;

    const int srow = t >> 1;
    const int sseg = (t & 1) << 4;

    if (MODE == 1 && t < 128) sBatch[t] = (r0 + t < N) ? batch[r0 + t] : -1;

    const bool arow_ok = (r0 + srow) < N;
    const unsigned short* ahRow = Ahp + (size_t)(r0 + srow) * KPf;
    const unsigned short* alRow = Alp + (size_t)(r0 + srow) * KPf;

    ushort8v rah0, rah1, ral0, ral1;
    ushort8v rbh[BIT][2], rbl[BIT][2];

    auto gload = [&](int kk) {
        int gk = kk + sseg;
        bool ok0 = arow_ok && (gk < KPf);
        bool ok1 = arow_ok && (gk + 8 < KPf);
        rah0 = ok0 ? *(const ushort8v*)(ahRow + gk) : zero8();
        rah1 = ok1 ? *(const ushort8v*)(ahRow + gk + 8) : zero8();
        ral0 = ok0 ? *(const ushort8v*)(alRow + gk) : zero8();
        ral1 = ok1 ? *(const ushort8v*)(alRow + gk + 8) : zero8();
#pragma unroll
        for (int it = 0; it < BIT; it++) {
            int item = it * 256 + t;
            int brow = item >> 1;
            int bseg = (item & 1) << 4;
            rbh[it][0] = zero8(); rbh[it][1] = zero8();
            rbl[it][0] = zero8(); rbl[it][1] = zero8();
            if (brow < CT) {
                int gc = c0 + brow;
                if (gc < Fout) {
                    const unsigned short* bh = Bth + (size_t)gc * KP + kk + bseg;
                    const unsigned short* bl = Btl + (size_t)gc * KP + kk + bseg;
                    rbh[it][0] = *(const ushort8v*)bh;
                    rbh[it][1] = *(const ushort8v*)(bh + 8);
                    rbl[it][0] = *(const ushort8v*)bl;
                    rbl[it][1] = *(const ushort8v*)(bl + 8);
                }
            }
        }
    };

    auto wlds = [&]() {
        int off = srow * LDST + sseg;
        *(ushort8v*)&sAh[off] = rah0;
        *(ushort8v*)&sAh[off + 8] = rah1;
        *(ushort8v*)&sAl[off] = ral0;
        *(ushort8v*)&sAl[off + 8] = ral1;
#pragma unroll
        for (int it = 0; it < BIT; it++) {
            int item = it * 256 + t;
            int brow = item >> 1;
            int bseg = (item & 1) << 4;
            if (brow < CT) {
                int boff = brow * LDST + bseg;
                *(ushort8v*)&sBh[boff] = rbh[it][0];
                *(ushort8v*)&sBh[boff + 8] = rbh[it][1];
                *(ushort8v*)&sBl[boff] = rbl[it][0];
                *(ushort8v*)&sBl[boff + 8] = rbl[it][1];
            }
        }
    };

    f32x4 acc[4][NJW];
#pragma unroll
    for (int i = 0; i < 4; i++)
#pragma unroll
        for (int j = 0; j < NJW; j++) acc[i][j] = (f32x4){0.f, 0.f, 0.f, 0.f};

    gload(0);
    for (int tc = 0; tc < nt; ++tc) {
        wlds();
        __syncthreads();
        if (tc + 1 < nt) gload((tc + 1) * 32);   // latency hides under MFMA below
        short8v ah[4], al[4];
#pragma unroll
        for (int i = 0; i < 4; i++) {
            int ro = (wrow + i * 16 + l15) * LDST + lk;
            ah[i] = *(const short8v*)&sAh[ro];
            al[i] = *(const short8v*)&sAl[ro];
        }
#pragma unroll
        for (int j = 0; j < NJW; j++) {
            int co = (wcol + j * 16 + l15) * LDST + lk;
            short8v bh = *(const short8v*)&sBh[co];
            short8v bl = *(const short8v*)&sBl[co];
#pragma unroll
            for (int i = 0; i < 4; i++) {
                acc[i][j] = __builtin_amdgcn_mfma_f32_16x16x32_bf16(al[i], bh, acc[i][j], 0, 0, 0);
                acc[i][j] = __builtin_amdgcn_mfma_f32_16x16x32_bf16(ah[i], bl, acc[i][j], 0, 0, 0);
                acc[i][j] = __builtin_amdgcn_mfma_f32_16x16x32_bf16(ah[i], bh, acc[i][j], 0, 0, 0);
            }
        }
        __syncthreads();
    }

    // per-thread row scales (C/D layout m89-verified: col = lane&15, row = (lane>>4)*4 + reg)
    float drw[16];
#pragma unroll
    for (int i = 0; i < 4; i++)
#pragma unroll
        for (int q = 0; q < 4; q++) {
            int gr = r0 + wrow + i * 16 + (lane >> 4) * 4 + q;
            drw[i * 4 + q] = (gr < N) ? dinvp[gr] : 0.f;
        }

    if (MODE == 0) {
#pragma unroll
        for (int j = 0; j < NJW; j++) {
            int gc = c0 + wcol + j * 16 + l15;
            if (gc >= CSbf) continue;
            float bv = (gc < Fout) ? bias[gc] : 0.f;
#pragma unroll
            for (int i = 0; i < 4; i++) {
                int rb = r0 + wrow + i * 16 + (lane >> 4) * 4;
#pragma unroll
                for (int q = 0; q < 4; q++) {
                    int gr = rb + q;
                    if (gr >= N) continue;
                    float dr = drw[i * 4 + q];
                    float vv = (gc < Fout) ? fmaxf(fmaf(acc[i][j][q], dr, bv), 0.f) * dr : 0.f;
                    Cb[(size_t)gr * CSbf + gc] = f2bf(vv);
                }
            }
        }
    } else {
#pragma unroll
        for (int j = 0; j < NJW; j++) {
            int gc = c0 + wcol + j * 16 + l15;
            if (gc >= Fout) continue;
            float bv = bias[gc];
            int gcur = -1;
            float vmax = 0.f;
#pragma unroll
            for (int i = 0; i < 4; i++) {
                int lr = wrow + i * 16 + (lane >> 4) * 4;
#pragma unroll
                for (int q = 0; q < 4; q++) {
                    int g = sBatch[lr + q];
                    float vv = fmaxf(fmaf(acc[i][j][q], drw[i * 4 + q], bv), 0.f);
                    if (g < 0) continue;
                    if (g != gcur) {
                        if (gcur >= 0)
                            atomicMax((int*)&G[(size_t)gcur * Fout + gc], __float_as_int(vmax));
                        gcur = g;
                        vmax = vv;
                    } else {
                        vmax = fmaxf(vmax, vv);
                    }
                }
            }
            if (gcur >= 0) atomicMax((int*)&G[(size_t)gcur * Fout + gc], __float_as_int(vmax));
        }
    }
}

// ---------------- fc_g1: C[M,Nout] = relu(A@W + b); 2 rows x 256 cols per block ----------

__global__ __launch_bounds__(256) void k_fc1(const float* __restrict__ A,
                                             const float* __restrict__ W,
                                             const float* __restrict__ bias,
                                             float* __restrict__ C,
                                             int M, int K, int Nout) {
    __shared__ float sA[2 * 304];
    const int t = threadIdx.x;
    const int m0 = blockIdx.x * 2;
    const int oc = blockIdx.y * 256 + t;

    for (int i = t; i < 2 * K; i += 256) {
        int r = i / K, k = i - r * K;
        sA[r * 304 + k] = (m0 + r < M) ? A[(size_t)(m0 + r) * K + k] : 0.f;
    }
    __syncthreads();

    float acc0 = 0.f, acc1 = 0.f;
    int k = 0;
    for (; k + 8 <= K; k += 8) {
        float w[8];
#pragma unroll
        for (int u = 0; u < 8; u++) w[u] = W[(size_t)(k + u) * Nout + oc];
#pragma unroll
        for (int u = 0; u < 8; u++) {
            acc0 = fmaf(sA[k + u], w[u], acc0);
            acc1 = fmaf(sA[304 + k + u], w[u], acc1);
        }
    }
    for (; k < K; k++) {
        float w = W[(size_t)k * Nout + oc];
        acc0 = fmaf(sA[k], w, acc0);
        acc1 = fmaf(sA[304 + k], w, acc1);
    }
    float bv = bias[oc];
    if (m0 < M) C[(size_t)m0 * Nout + oc] = fmaxf(acc0 + bv, 0.f);
    if (m0 + 1 < M) C[(size_t)(m0 + 1) * Nout + oc] = fmaxf(acc1 + bv, 0.f);
}

// ---------------- fc_g2: split-K partial (KS=256) + deterministic reduce ----------------

__global__ __launch_bounds__(256) void k_fc2p(const float* __restrict__ A,
                                              const float* __restrict__ W,
                                              float* __restrict__ P,
                                              int M, int K, int Nout) {
    __shared__ float sA[2 * 256];
    const int t = threadIdx.x;
    const int m0 = blockIdx.x * 2;
    const int sk = blockIdx.y;
    const int k0 = sk * 256;
    const int row = t >> 7;
    const int oc = t & 127;

    for (int i = t; i < 2 * 256; i += 256) {
        int r = i >> 8, k = i & 255;
        sA[i] = (m0 + r < M) ? A[(size_t)(m0 + r) * K + k0 + k] : 0.f;
    }
    __syncthreads();

    const float* a = sA + row * 256;
    float acc = 0.f;
    for (int k = 0; k < 256; k += 8) {
        float w[8];
#pragma unroll
        for (int u = 0; u < 8; u++) w[u] = W[(size_t)(k0 + k + u) * Nout + oc];
#pragma unroll
        for (int u = 0; u < 8; u++) acc = fmaf(a[k + u], w[u], acc);
    }
    int m = m0 + row;
    if (m < M) P[((size_t)sk * M + m) * Nout + oc] = acc;
}

__global__ __launch_bounds__(256) void k_fc2r(const float* __restrict__ P,
                                              const float* __restrict__ bias,
                                              float* __restrict__ C,
                                              int M, int Nout, int SK) {
    int i = blockIdx.x * blockDim.x + threadIdx.x;
    if (i >= M * Nout) return;
    int oc = i % Nout;
    float acc = bias[oc];
    for (int s2 = 0; s2 < SK; s2++) acc += P[(size_t)s2 * M * Nout + i];
    C[i] = acc;
}

// ---------------- launch ----------------

extern "C" void kernel_launch(void* const* d_in, const int* in_sizes, int n_in,
                              void* d_out, int out_size, void* d_ws, size_t ws_size,
                              hipStream_t stream) {
    const float* x     = (const float*)d_in[0];
    const int*   ei    = (const int*)d_in[1];
    const int*   batch = (const int*)d_in[2];
    const float* W1 = (const float*)d_in[3];
    const float* b1 = (const float*)d_in[4];
    const float* W2 = (const float*)d_in[5];
    const float* b2 = (const float*)d_in[6];
    const float* W3 = (const float*)d_in[7];
    const float* b3 = (const float*)d_in[8];
    const float* Wg1 = (const float*)d_in[9];
    const float* bg1 = (const float*)d_in[10];
    const float* Wg2 = (const float*)d_in[11];
    const float* bg2 = (const float*)d_in[12];

    const int N  = in_sizes[2];          // 50000
    const int E  = in_sizes[1] / 2;      // 800000
    const int F1 = in_sizes[4];          // 75
    const int F2 = in_sizes[6];          // 150
    const int F3 = in_sizes[8];          // 300
    const int H1 = in_sizes[10];         // 1024
    const int OC = in_sizes[12];         // 128
    const int NG = out_size / OC;        // 256
    const int FIN = in_sizes[3] / F1;    // 75

    const int KP1 = 96,  KPf1 = 80;      // K=75 padded (GEMM loop / A-plane stride)
    const int KP3 = 160, KPf3 = 152;     // K=150 padded
    const int XS0 = 80;                  // x bf16 (pre-scaled) row stride
    const int HS1 = 80;                  // Y1 bf16 row stride
    const int HS2 = 152;                 // Y2 bf16 row stride

    const int* src = ei;
    const int* dst = ei + E;

    char* base = (char*)d_ws;
    size_t off = 0;
    auto alloc = [&](size_t bytes) -> void* {
        void* p = base + off;
        off = (off + bytes + 255) & ~(size_t)255;
        return p;
    };
    int*   cnt    = (int*)alloc((size_t)N * 4);
    int*   fill   = (int*)alloc((size_t)N * 4);
    int*   rowptr = (int*)alloc((size_t)(N + 1) * 4);
    float* dinv   = (float*)alloc((size_t)N * 4);
    int*   bsum   = (int*)alloc(256 * 4);
    int*   col    = (int*)alloc((size_t)E * 4);
    unsigned short* W1th = (unsigned short*)alloc((size_t)F1 * KP1 * 2);
    unsigned short* W1tl = (unsigned short*)alloc((size_t)F1 * KP1 * 2);
    unsigned short* W2th = (unsigned short*)alloc((size_t)F2 * KP1 * 2);
    unsigned short* W2tl = (unsigned short*)alloc((size_t)F2 * KP1 * 2);
    unsigned short* W3th = (unsigned short*)alloc((size_t)F3 * KP3 * 2);
    unsigned short* W3tl = (unsigned short*)alloc((size_t)F3 * KP3 * 2);
    float* Gb  = (float*)alloc((size_t)NG * F3 * 4);
    float* g1  = (float*)alloc((size_t)NG * H1 * 4);
    float* P2  = (float*)alloc((size_t)4 * NG * OC * 4);                // split-K partials
    unsigned short* TgH = (unsigned short*)alloc((size_t)N * KPf3 * 2); // 15.2 MB hi plane
    unsigned short* TgL = (unsigned short*)alloc((size_t)N * KPf3 * 2); // 15.2 MB lo plane
    unsigned short* Xb  = (unsigned short*)alloc((size_t)N * XS0 * 2);  // 8 MB bf16 scaled x
    unsigned short* H1b = (unsigned short*)alloc((size_t)N * HS1 * 2);  // 8 MB bf16
    unsigned short* H2b = (unsigned short*)alloc((size_t)N * HS2 * 2);  // 15.2 MB bf16

    hipMemsetAsync(cnt, 0, (size_t)N * 4, stream);
    hipMemsetAsync(fill, 0, (size_t)N * 4, stream);
    hipMemsetAsync(Gb, 0, (size_t)NG * F3 * 4, stream);

    // ---- CSR ----
    k_count<<<ceil_div_i(E, 256), 256, 0, stream>>>(dst, E, cnt);
    k_dinv<<<ceil_div_i(N, 256), 256, 0, stream>>>(cnt, dinv, N);
    int NB = ceil_div_i(N, SCAN_B);
    k_scan1<<<NB, 256, 0, stream>>>(cnt, rowptr, bsum, N);
    k_scan2<<<1, 256, 0, stream>>>(bsum, NB);
    k_scan3<<<ceil_div_i(N, 256), 256, 0, stream>>>(rowptr, bsum, N, E);
    k_fill<<<ceil_div_i(E, 256), 256, 0, stream>>>(src, dst, E, rowptr, fill, col);

    // ---- weight splits + scaled-x (small) ----
    k_wsplit<<<ceil_div_i((long long)F1 * KP1, 256), 256, 0, stream>>>(W1, W1th, W1tl, FIN, F1, KP1);
    k_wsplit<<<ceil_div_i((long long)F2 * KP1, 256), 256, 0, stream>>>(W2, W2th, W2tl, F1, F2, KP1);
    k_wsplit<<<ceil_div_i((long long)F3 * KP3, 256), 256, 0, stream>>>(W3, W3th, W3tl, F2, F3, KP3);
    k_xscale<<<ceil_div_i((long long)N * XS0, 256), 256, 0, stream>>>(x, dinv, Xb, N, FIN, XS0);

    dim3 blk(256);
    int gw = ceil_div_i(N, 4);
    int gx = ceil_div_i(N, 128);

    // conv1: gather Xb (10 chunks x 6 slots) -> TgH/TgL stride 80; GEMM CT=96 covers 75
    k_gather_s<10, 6, 2><<<gw, blk, 0, stream>>>(Xb, rowptr, col, TgH, TgL, N, XS0, KPf1);
    {
        dim3 g(gx, 1);
        k_gemm_mfma<3, 0><<<g, blk, 0, stream>>>(TgH, TgL, KPf1, W1th, W1tl, b1, dinv,
                                                 H1b, HS1, nullptr, nullptr, N, KP1, F1);
    }
    // conv2: gather Y1 -> TgH/TgL stride 80; GEMM CT=160 covers 150
    k_gather_s<10, 6, 2><<<gw, blk, 0, stream>>>(H1b, rowptr, col, TgH, TgL, N, HS1, KPf1);
    {
        dim3 g(gx, 1);
        k_gemm_mfma<5, 0><<<g, blk, 0, stream>>>(TgH, TgL, KPf1, W2th, W2tl, b2, dinv,
                                                 H2b, HS2, nullptr, nullptr, N, KP1, F2);
    }
    // conv3: gather Y2 (19 chunks x 3 slots) -> stride 152; GEMM CT=160 x2, fused pool
    k_gather_s<19, 3, 4><<<gw, blk, 0, stream>>>(H2b, rowptr, col, TgH, TgL, N, HS2, KPf3);
    {
        dim3 g(gx, 2);
        k_gemm_mfma<5, 1><<<g, blk, 0, stream>>>(TgH, TgL, KPf3, W3th, W3tl, b3, dinv,
                                                 nullptr, 0, batch, Gb, N, KP3, F3);
    }

    // fc_g1: 2 rows x 256 cols per block -> grid (128, 4) = 512 blocks
    {
        dim3 g(ceil_div_i(NG, 2), H1 / 256);
        k_fc1<<<g, 256, 0, stream>>>(Gb, Wg1, bg1, g1, NG, F3, H1);
    }
    // fc_g2: split-K=4 partials (512 blocks) + deterministic reduce
    {
        dim3 g(ceil_div_i(NG, 2), 4);
        k_fc2p<<<g, 256, 0, stream>>>(g1, Wg2, P2, NG, H1, OC);
        k_fc2r<<<ceil_div_i((long long)NG * OC, 256), 256, 0, stream>>>(
            P2, bg2, (float*)d_out, NG, OC, 4);
    }
}